// Round 8
// baseline (197.841 us; speedup 1.0000x reference)
//
#include <hip/hip_runtime.h>

typedef unsigned short u16;
typedef unsigned int   u32;
typedef __attribute__((ext_vector_type(8))) short bf16x8;
typedef __attribute__((ext_vector_type(4))) float f32x4;
typedef __attribute__((ext_vector_type(2))) unsigned int u32x2;

__device__ __forceinline__ float bf2f(u16 u) { return __uint_as_float(((u32)u) << 16); }
// round-half-up (ties away): identical to RNE except exact ties; 2 VALU ops.
__device__ __forceinline__ u16 f2bf(float f) {
    return (u16)((__float_as_uint(f) + 0x8000u) >> 16);
}
__device__ __forceinline__ void gload16(const void* g, void* l) {
    __builtin_amdgcn_global_load_lds((const __attribute__((address_space(1))) void*)g,
                                     (__attribute__((address_space(3))) void*)l, 16, 0, 0);
}

// ---------------------------------------------------------------------------
// Fused fp32->bf16 conversion for hs + Wq + Wk + Wv (contiguous dsts in ws).
// ---------------------------------------------------------------------------
struct us4 { u16 x, y, z, w; };
__global__ void cvt_all(const float* __restrict__ hs, const float* __restrict__ wq,
                        const float* __restrict__ wk, const float* __restrict__ wv,
                        u16* __restrict__ dst)
{
    int i = blockIdx.x * blockDim.x + threadIdx.x;
    const int stride = gridDim.x * blockDim.x;
    us4* d4 = (us4*)dst;
    for (; i < 1835008; i += stride) {
        const float4* s4;
        int j = i;
        if (j < 1048576)      { s4 = (const float4*)hs; }
        else if (j < 1310720) { s4 = (const float4*)wq; j -= 1048576; }
        else if (j < 1572864) { s4 = (const float4*)wk; j -= 1310720; }
        else                  { s4 = (const float4*)wv; j -= 1572864; }
        float4 v = s4[j];
        us4 o;
        o.x = f2bf(v.x); o.y = f2bf(v.y); o.z = f2bf(v.z); o.w = f2bf(v.w);
        d4[i] = o;
    }
}

// ---------------------------------------------------------------------------
// Kernel 1: fused QKV projection (unchanged from R7).  64x128 tile, BK=64,
// grid 64x24 = 1536 blocks = 6/CU.  Q,K out [b,h,n,d]; V out transposed.
// ---------------------------------------------------------------------------
__global__ __launch_bounds__(256) void qkv_gemm(
    const u16* __restrict__ hs,
    const u16* __restrict__ Wq, const u16* __restrict__ Wk, const u16* __restrict__ Wv,
    const float* __restrict__ bq, const float* __restrict__ bk, const float* __restrict__ bv,
    u16* __restrict__ oq, u16* __restrict__ ok, u16* __restrict__ ovt)
{
    __shared__ u16 smem[12288];        // sA 64x64 [0,4096), sB 128x64 [4096,12288)
    u16* sA = smem;
    u16* sB = smem + 4096;

    const int tid  = threadIdx.x;
    const int lane = tid & 63;
    const int wv_  = tid >> 6;
    const int c15  = lane & 15;
    const int q4   = lane >> 4;
    const int rb   = blockIdx.x;        // row block 0..63 (64 rows)
    const int mat  = blockIdx.y >> 3;   // 0=q 1=k 2=v
    const int cb   = blockIdx.y & 7;    // col block 0..7 (128 cols)

    const u16*   W    = (mat == 0) ? Wq : (mat == 1 ? Wk : Wv);
    const float* bias = (mat == 0) ? bq : (mat == 1 ? bk : bv);

    f32x4 acc[4][2] = {};

    int rA[2], cA[2], rB[4], cB[4];
#pragma unroll
    for (int p = 0; p < 2; ++p) {
        const int ch = p * 256 + tid;
        rA[p] = ch >> 3; cA[p] = ((ch & 7) ^ (rA[p] & 7)) * 8;
    }
#pragma unroll
    for (int p = 0; p < 4; ++p) {
        const int ch = p * 256 + tid;
        rB[p] = ch >> 3; cB[p] = ((ch & 7) ^ (rB[p] & 7)) * 8;
    }
    const u16* gA = hs + (rb * 64) * 1024;
    const u16* gB = W + (cb * 128) * 1024;
    const int swz = c15 & 7;

    for (int kb = 0; kb < 1024; kb += 64) {
        __syncthreads();
#pragma unroll
        for (int p = 0; p < 2; ++p)
            gload16(gA + rA[p] * 1024 + kb + cA[p], sA + (p * 256 + wv_ * 64) * 8);
#pragma unroll
        for (int p = 0; p < 4; ++p)
            gload16(gB + rB[p] * 1024 + kb + cB[p], sB + (p * 256 + wv_ * 64) * 8);
        __syncthreads();

#pragma unroll
        for (int kk = 0; kk < 2; ++kk) {
            const int cpos = ((kk * 4 + q4) ^ swz) * 8;
            bf16x8 af[4], bf[2];
#pragma unroll
            for (int mt = 0; mt < 4; ++mt)
                af[mt] = *(const bf16x8*)(sA + (mt * 16 + c15) * 64 + cpos);
#pragma unroll
            for (int nt = 0; nt < 2; ++nt)
                bf[nt] = *(const bf16x8*)(sB + (wv_ * 32 + nt * 16 + c15) * 64 + cpos);
#pragma unroll
            for (int mt = 0; mt < 4; ++mt)
#pragma unroll
                for (int nt = 0; nt < 2; ++nt)
                    acc[mt][nt] = __builtin_amdgcn_mfma_f32_16x16x32_bf16(
                        af[mt], bf[nt], acc[mt][nt], 0, 0, 0);
        }
    }

    // ---- epilogue: bias add, per-wave LDS transpose, coalesced 16B stores ----
    __syncthreads();
    const int hcol = cb * 2 + (wv_ >> 1);
    const int dbase = (wv_ & 1) * 32;
    float bvv[2];
#pragma unroll
    for (int nt = 0; nt < 2; ++nt)
        bvv[nt] = bias[cb * 128 + wv_ * 32 + nt * 16 + c15];

    u16* sc = smem + wv_ * 2560;
    if (mat != 2) {
        u16* dst = (mat == 0) ? oq : ok;
#pragma unroll
        for (int mt = 0; mt < 4; ++mt)
#pragma unroll
            for (int nt = 0; nt < 2; ++nt)
#pragma unroll
                for (int r = 0; r < 4; ++r)
                    sc[(mt * 16 + q4 * 4 + r) * 40 + nt * 16 + c15] =
                        f2bf(acc[mt][nt][r] + bvv[nt]);
#pragma unroll
        for (int i = 0; i < 4; ++i) {
            const int rl = i * 16 + (lane >> 2);
            const int c0 = (lane & 3) * 8;
            bf16x8 vv = *(const bf16x8*)(sc + rl * 40 + c0);
            const int n = rb * 64 + rl;
            const int bb = n >> 11, nn = n & 2047;
            *(bf16x8*)(dst + (((bb * 16 + hcol) * 2048) + nn) * 64 + dbase + c0) = vv;
        }
    } else {
#pragma unroll
        for (int mt = 0; mt < 4; ++mt)
#pragma unroll
            for (int nt = 0; nt < 2; ++nt)
#pragma unroll
                for (int r = 0; r < 4; ++r)
                    sc[(nt * 16 + c15) * 72 + mt * 16 + q4 * 4 + r] =
                        f2bf(acc[mt][nt][r] + bvv[nt]);
#pragma unroll
        for (int i = 0; i < 4; ++i) {
            const int dp = i * 8 + (lane >> 3);
            const int nl = (lane & 7) * 8;
            bf16x8 vv = *(const bf16x8*)(sc + dp * 72 + nl);
            const int n = rb * 64 + nl;
            const int bb = n >> 11, nn = n & 2047;
            *(bf16x8*)(ovt + (((bb * 16 + hcol) * 64) + dbase + dp) * 2048 + nn) = vv;
        }
    }
}

// ---------------------------------------------------------------------------
// Kernel 2: flash attention, S^T formulation — P stays in registers.
// QK computed as S^T = K·Q^T (A=K, B=Q): C-layout gives lane (q4,c15) element
// S[qrow=c15][key=q4*4+r].  After exp, that IS the A-operand layout of P for a
// K16 PV step; we emulate K16 exactly with the K32 intrinsic by zero-padding
// the high half of each lane's A/B fragments (virtual k%8>=4 terms vanish).
// -> zero DS writes in the hot loop: 8 ds_read_b128 (K) + 16 ds_read_b64 (V^T)
// per wave-iter (was 84 DS instr incl. 64 b16 writes).  sP deleted.
// l accumulated per-lane (at c15=qrow), reduced once at end (2 shfls) and
// rebroadcast per output row (4 shfls).
// ---------------------------------------------------------------------------
__global__ __launch_bounds__(256) void attn(
    const u16* __restrict__ qm, const u16* __restrict__ km, const u16* __restrict__ vtm,
    const float* __restrict__ mask, float* __restrict__ out)
{
    __shared__ u16 sK[64 * 64];        // [key][d-chunk], XOR-swizzled by key&7
    __shared__ u16 sVT[64 * 64];       // [d][key-chunk], XOR-swizzled by d&7

    const int tid = threadIdx.x, lane = tid & 63, w = tid >> 6;
    const int c15 = lane & 15, q4 = lane >> 4;
    const int qt = blockIdx.x;         // q tile 0..15 (128 rows each)
    const int bh = blockIdx.y;         // 0..31
    const int b = bh >> 4;

    // Q fragments (used as B operand of S^T = K·Q^T; same register content
    // as the A-layout load: Q[qrow=c15][d=q4*8+j])
    bf16x8 qf[2][2];
    const u16* qbase = qm + (bh * 2048 + qt * 128 + w * 32) * 64;
#pragma unroll
    for (int rt = 0; rt < 2; ++rt)
#pragma unroll
        for (int kt = 0; kt < 2; ++kt)
            qf[rt][kt] = *(const bf16x8*)(qbase + (rt * 16 + c15) * 64 + kt * 32 + q4 * 8);

    float l_acc[2] = {0.f, 0.f};
    f32x4 accO[2][4] = {};

    const u16* kbase  = km  + bh * 2048 * 64;
    const u16* vtbase = vtm + bh * 64 * 2048;   // [d][n]

    // staging chunk decomposition (each 64x64 tile = 512 chunks, 2/thread)
    const int r0 = tid >> 3,         cc0 = ((tid & 7) ^ (r0 & 7)) * 8;
    const int r1 = (256 + tid) >> 3, cc1 = ((tid & 7) ^ (r1 & 7)) * 8;

    for (int it = 0; it < 32; ++it) {
        const int kb = it * 64;
        __syncthreads();               // prior iter's sK/sVT reads done

        gload16(kbase + (kb + r0) * 64 + cc0, sK + (w * 64) * 8);        // K [key][d]
        gload16(kbase + (kb + r1) * 64 + cc1, sK + (256 + w * 64) * 8);
        gload16(vtbase + r0 * 2048 + kb + cc0, sVT + (w * 64) * 8);      // V^T [d][key]
        gload16(vtbase + r1 * 2048 + kb + cc1, sVT + (256 + w * 64) * 8);
        __syncthreads();               // staging resident

        // mask per key (key = kb + ktile*16 + q4*4 + r) — 4 aligned float4 loads
        float mkv[4][4];
#pragma unroll
        for (int ktile = 0; ktile < 4; ++ktile) {
            float4 m4 = *(const float4*)(mask + b * 2048 + kb + ktile * 16 + q4 * 4);
            mkv[ktile][0] = m4.x; mkv[ktile][1] = m4.y;
            mkv[ktile][2] = m4.z; mkv[ktile][3] = m4.w;
        }

        // --- S^T = K Q^T: D[key][qrow]; kf shared across rt
        f32x4 accST[4][2] = {};
#pragma unroll
        for (int kt = 0; kt < 2; ++kt) {
            bf16x8 kf[4];
#pragma unroll
            for (int ktile = 0; ktile < 4; ++ktile) {
                const int key = ktile * 16 + c15;
                const int cpos = (kt * 4 + q4) ^ (key & 7);
                kf[ktile] = *(const bf16x8*)(sK + key * 64 + cpos * 8);
            }
#pragma unroll
            for (int ktile = 0; ktile < 4; ++ktile)
#pragma unroll
                for (int rt = 0; rt < 2; ++rt)
                    accST[ktile][rt] = __builtin_amdgcn_mfma_f32_16x16x32_bf16(
                        kf[ktile], qf[rt][kt], accST[ktile][rt], 0, 0, 0);
        }

        // --- per 16-key tile: softmax in-register, PV via zero-padded K32 MFMA
#pragma unroll
        for (int ktile = 0; ktile < 4; ++ktile) {
            // B-frags: V[key][d] from sVT b64 (4 keys) + zero high half
            bf16x8 vB[4];
#pragma unroll
            for (int nt = 0; nt < 4; ++nt) {
                const int d = nt * 16 + c15;
                const int pc = (ktile * 2 + (q4 >> 1)) ^ (d & 7);
                u32x2 pr = *(const u32x2*)(sVT + d * 64 + pc * 8 + (q4 & 1) * 4);
                union { bf16x8 v; u32 u[4]; } t;
                t.u[0] = pr.x; t.u[1] = pr.y; t.u[2] = 0; t.u[3] = 0;
                vB[nt] = t.v;
            }
            // A-frags: p = exp(s/8 + mask), packed bf16 pairs + zero high half
            bf16x8 pA[2];
#pragma unroll
            for (int rt = 0; rt < 2; ++rt) {
                u32 a[4];
#pragma unroll
                for (int r = 0; r < 4; ++r) {
                    const float p = __expf(fmaf(accST[ktile][rt][r], 0.125f, mkv[ktile][r]));
                    l_acc[rt] += p;
                    a[r] = __float_as_uint(p) + 0x8000u;   // round-half-up bf16 bits<<16
                }
                union { bf16x8 v; u32 u[4]; } t;
                t.u[0] = (a[0] >> 16) | (a[1] & 0xFFFF0000u);
                t.u[1] = (a[2] >> 16) | (a[3] & 0xFFFF0000u);
                t.u[2] = 0; t.u[3] = 0;
                pA[rt] = t.v;
            }
#pragma unroll
            for (int rt = 0; rt < 2; ++rt)
#pragma unroll
                for (int nt = 0; nt < 4; ++nt)
                    accO[rt][nt] = __builtin_amdgcn_mfma_f32_16x16x32_bf16(
                        pA[rt], vB[nt], accO[rt][nt], 0, 0, 0);
        }
    }

    // --- l reduction: lanes sharing c15 (q4 groups) -> total per qrow=c15
#pragma unroll
    for (int rt = 0; rt < 2; ++rt) {
        l_acc[rt] += __shfl_xor(l_acc[rt], 16);
        l_acc[rt] += __shfl_xor(l_acc[rt], 32);
    }

    // --- epilogue: accO C-layout row=q4*4+r=qrow, col=c15=d; l rebroadcast
    const int h = bh & 15;
#pragma unroll
    for (int rt = 0; rt < 2; ++rt) {
        float inv[4];
#pragma unroll
        for (int r = 0; r < 4; ++r)
            inv[r] = 1.0f / __shfl(l_acc[rt], q4 * 4 + r);
#pragma unroll
        for (int nt = 0; nt < 4; ++nt)
#pragma unroll
            for (int r = 0; r < 4; ++r) {
                const int qrow = qt * 128 + w * 32 + rt * 16 + q4 * 4 + r;
                const int d = nt * 16 + c15;
                out[(b * 2048 + qrow) * 1024 + h * 64 + d] = accO[rt][nt][r] * inv[r];
            }
    }
}

// ---------------------------------------------------------------------------
extern "C" void kernel_launch(void* const* d_in, const int* in_sizes, int n_in,
                              void* d_out, int out_size, void* d_ws, size_t ws_size,
                              hipStream_t stream)
{
    const float* hs   = (const float*)d_in[0];
    const float* mask = (const float*)d_in[1];
    const float* Wq   = (const float*)d_in[2];
    const float* bq   = (const float*)d_in[3];
    const float* Wk   = (const float*)d_in[4];
    const float* bk   = (const float*)d_in[5];
    const float* Wv   = (const float*)d_in[6];
    const float* bv   = (const float*)d_in[7];

    // workspace layout (u16 units)
    u16* ws   = (u16*)d_ws;
    u16* qw   = ws;                     // Q  [b,h,n,d] bf16
    u16* kw   = ws + 4194304;           // K  [b,h,n,d]
    u16* vtw  = ws + 8388608;           // V^T [b,h,d,n]
    u16* hsb  = ws + 12582912;          // hidden_states bf16 (cvt_all dst start)
    u16* wqb  = ws + 16777216;
    u16* wkb  = ws + 17825792;
    u16* wvb  = ws + 18874368;

    cvt_all<<<1024, 256, 0, stream>>>(hs, Wq, Wk, Wv, hsb);

    qkv_gemm<<<dim3(64, 24), 256, 0, stream>>>(hsb, wqb, wkb, wvb, bq, bk, bv, qw, kw, vtw);
    attn<<<dim3(16, 32), 256, 0, stream>>>(qw, kw, vtw, mask, (float*)d_out);
}

// Round 9
// 178.644 us; speedup vs baseline: 1.1075x; 1.1075x over previous
//
#include <hip/hip_runtime.h>

typedef unsigned short u16;
typedef unsigned int   u32;
typedef __attribute__((ext_vector_type(8))) short bf16x8;
typedef __attribute__((ext_vector_type(4))) float f32x4;
typedef __attribute__((ext_vector_type(2))) unsigned int u32x2;

__device__ __forceinline__ float bf2f(u16 u) { return __uint_as_float(((u32)u) << 16); }
// round-half-up (ties away): identical to RNE except exact ties; 2 VALU ops.
__device__ __forceinline__ u16 f2bf(float f) {
    return (u16)((__float_as_uint(f) + 0x8000u) >> 16);
}
__device__ __forceinline__ void gload16(const void* g, void* l) {
    __builtin_amdgcn_global_load_lds((const __attribute__((address_space(1))) void*)g,
                                     (__attribute__((address_space(3))) void*)l, 16, 0, 0);
}

// ---------------------------------------------------------------------------
// Fused fp32->bf16 conversion for hs + Wq + Wk + Wv (contiguous dsts in ws).
// ---------------------------------------------------------------------------
struct us4 { u16 x, y, z, w; };
__global__ void cvt_all(const float* __restrict__ hs, const float* __restrict__ wq,
                        const float* __restrict__ wk, const float* __restrict__ wv,
                        u16* __restrict__ dst)
{
    int i = blockIdx.x * blockDim.x + threadIdx.x;
    const int stride = gridDim.x * blockDim.x;
    us4* d4 = (us4*)dst;
    for (; i < 1835008; i += stride) {
        const float4* s4;
        int j = i;
        if (j < 1048576)      { s4 = (const float4*)hs; }
        else if (j < 1310720) { s4 = (const float4*)wq; j -= 1048576; }
        else if (j < 1572864) { s4 = (const float4*)wk; j -= 1310720; }
        else                  { s4 = (const float4*)wv; j -= 1572864; }
        float4 v = s4[j];
        us4 o;
        o.x = f2bf(v.x); o.y = f2bf(v.y); o.z = f2bf(v.z); o.w = f2bf(v.w);
        d4[i] = o;
    }
}

// ---------------------------------------------------------------------------
// Kernel 1: fused QKV projection (unchanged from R7).  64x128 tile, BK=64,
// grid 64x24 = 1536 blocks = 6/CU.  Q,K out [b,h,n,d]; V out transposed.
// ---------------------------------------------------------------------------
__global__ __launch_bounds__(256) void qkv_gemm(
    const u16* __restrict__ hs,
    const u16* __restrict__ Wq, const u16* __restrict__ Wk, const u16* __restrict__ Wv,
    const float* __restrict__ bq, const float* __restrict__ bk, const float* __restrict__ bv,
    u16* __restrict__ oq, u16* __restrict__ ok, u16* __restrict__ ovt)
{
    __shared__ u16 smem[12288];        // sA 64x64 [0,4096), sB 128x64 [4096,12288)
    u16* sA = smem;
    u16* sB = smem + 4096;

    const int tid  = threadIdx.x;
    const int lane = tid & 63;
    const int wv_  = tid >> 6;
    const int c15  = lane & 15;
    const int q4   = lane >> 4;
    const int rb   = blockIdx.x;        // row block 0..63 (64 rows)
    const int mat  = blockIdx.y >> 3;   // 0=q 1=k 2=v
    const int cb   = blockIdx.y & 7;    // col block 0..7 (128 cols)

    const u16*   W    = (mat == 0) ? Wq : (mat == 1 ? Wk : Wv);
    const float* bias = (mat == 0) ? bq : (mat == 1 ? bk : bv);

    f32x4 acc[4][2] = {};

    int rA[2], cA[2], rB[4], cB[4];
#pragma unroll
    for (int p = 0; p < 2; ++p) {
        const int ch = p * 256 + tid;
        rA[p] = ch >> 3; cA[p] = ((ch & 7) ^ (rA[p] & 7)) * 8;
    }
#pragma unroll
    for (int p = 0; p < 4; ++p) {
        const int ch = p * 256 + tid;
        rB[p] = ch >> 3; cB[p] = ((ch & 7) ^ (rB[p] & 7)) * 8;
    }
    const u16* gA = hs + (rb * 64) * 1024;
    const u16* gB = W + (cb * 128) * 1024;
    const int swz = c15 & 7;

    for (int kb = 0; kb < 1024; kb += 64) {
        __syncthreads();
#pragma unroll
        for (int p = 0; p < 2; ++p)
            gload16(gA + rA[p] * 1024 + kb + cA[p], sA + (p * 256 + wv_ * 64) * 8);
#pragma unroll
        for (int p = 0; p < 4; ++p)
            gload16(gB + rB[p] * 1024 + kb + cB[p], sB + (p * 256 + wv_ * 64) * 8);
        __syncthreads();

#pragma unroll
        for (int kk = 0; kk < 2; ++kk) {
            const int cpos = ((kk * 4 + q4) ^ swz) * 8;
            bf16x8 af[4], bf[2];
#pragma unroll
            for (int mt = 0; mt < 4; ++mt)
                af[mt] = *(const bf16x8*)(sA + (mt * 16 + c15) * 64 + cpos);
#pragma unroll
            for (int nt = 0; nt < 2; ++nt)
                bf[nt] = *(const bf16x8*)(sB + (wv_ * 32 + nt * 16 + c15) * 64 + cpos);
#pragma unroll
            for (int mt = 0; mt < 4; ++mt)
#pragma unroll
                for (int nt = 0; nt < 2; ++nt)
                    acc[mt][nt] = __builtin_amdgcn_mfma_f32_16x16x32_bf16(
                        af[mt], bf[nt], acc[mt][nt], 0, 0, 0);
        }
    }

    // ---- epilogue: bias add, per-wave LDS transpose, coalesced 16B stores ----
    __syncthreads();
    const int hcol = cb * 2 + (wv_ >> 1);
    const int dbase = (wv_ & 1) * 32;
    float bvv[2];
#pragma unroll
    for (int nt = 0; nt < 2; ++nt)
        bvv[nt] = bias[cb * 128 + wv_ * 32 + nt * 16 + c15];

    u16* sc = smem + wv_ * 2560;
    if (mat != 2) {
        u16* dst = (mat == 0) ? oq : ok;
#pragma unroll
        for (int mt = 0; mt < 4; ++mt)
#pragma unroll
            for (int nt = 0; nt < 2; ++nt)
#pragma unroll
                for (int r = 0; r < 4; ++r)
                    sc[(mt * 16 + q4 * 4 + r) * 40 + nt * 16 + c15] =
                        f2bf(acc[mt][nt][r] + bvv[nt]);
#pragma unroll
        for (int i = 0; i < 4; ++i) {
            const int rl = i * 16 + (lane >> 2);
            const int c0 = (lane & 3) * 8;
            bf16x8 vv = *(const bf16x8*)(sc + rl * 40 + c0);
            const int n = rb * 64 + rl;
            const int bb = n >> 11, nn = n & 2047;
            *(bf16x8*)(dst + (((bb * 16 + hcol) * 2048) + nn) * 64 + dbase + c0) = vv;
        }
    } else {
#pragma unroll
        for (int mt = 0; mt < 4; ++mt)
#pragma unroll
            for (int nt = 0; nt < 2; ++nt)
#pragma unroll
                for (int r = 0; r < 4; ++r)
                    sc[(nt * 16 + c15) * 72 + mt * 16 + q4 * 4 + r] =
                        f2bf(acc[mt][nt][r] + bvv[nt]);
#pragma unroll
        for (int i = 0; i < 4; ++i) {
            const int dp = i * 8 + (lane >> 3);
            const int nl = (lane & 7) * 8;
            bf16x8 vv = *(const bf16x8*)(sc + dp * 72 + nl);
            const int n = rb * 64 + nl;
            const int bb = n >> 11, nn = n & 2047;
            *(bf16x8*)(ovt + (((bb * 16 + hcol) * 64) + dbase + dp) * 2048 + nn) = vv;
        }
    }
}

// ---------------------------------------------------------------------------
// Kernel 2: flash attention, S^T formulation with in-register P and FULL-K32
// PV via a custom virtual key ordering.
//   S^T = K·Q^T: lane(q4,c15) reg r holds S[key=ktile*16+q4*4+r][qrow=c15].
//   After exp + bf16-pack, a 32-key group (ktile pair 2g,2g+1) forms a complete
//   K32 A-fragment IN REGISTERS with virtual key order
//     k=(q4,j) -> real key 32g + 16*(j>>2) + 4*q4 + (j&3).
//   V B-frags follow the same order: two ds_read_b64 per nt (keys 4q4..4q4+3
//   contiguous in sVT rows).
// DS per wave-iter: 8 ds_read_b128 (K) + 16 ds_read_b64 (V) — no P writes,
// no shuffles (R7 had 84 DS ops incl. 64 b16 writes; R8's K16 pad doubled PV
// MFMA).  MFMA count = R7's 32.  sP deleted (LDS 16.5 KB).
// ---------------------------------------------------------------------------
__global__ __launch_bounds__(256) void attn(
    const u16* __restrict__ qm, const u16* __restrict__ km, const u16* __restrict__ vtm,
    const float* __restrict__ mask, float* __restrict__ out)
{
    __shared__ u16 sK[64 * 64];        // [key][d-chunk], XOR-swizzled by key&7
    __shared__ u16 sVT[64 * 64];       // [d][key-chunk], XOR-swizzled by d&7

    const int tid = threadIdx.x, lane = tid & 63, w = tid >> 6;
    const int c15 = lane & 15, q4 = lane >> 4;
    const int qt = blockIdx.x;         // q tile 0..15 (128 rows each)
    const int bh = blockIdx.y;         // 0..31
    const int b = bh >> 4;

    // Q fragments (B operand of S^T = K·Q^T): Q[qrow=c15][d=q4*8+j]
    bf16x8 qf[2][2];
    const u16* qbase = qm + (bh * 2048 + qt * 128 + w * 32) * 64;
#pragma unroll
    for (int rt = 0; rt < 2; ++rt)
#pragma unroll
        for (int kt = 0; kt < 2; ++kt)
            qf[rt][kt] = *(const bf16x8*)(qbase + (rt * 16 + c15) * 64 + kt * 32 + q4 * 8);

    float l_acc[2] = {0.f, 0.f};
    f32x4 accO[2][4] = {};

    const u16* kbase  = km  + bh * 2048 * 64;
    const u16* vtbase = vtm + bh * 64 * 2048;   // [d][n]

    // staging chunk decomposition (each 64x64 tile = 512 chunks, 2/thread)
    const int r0 = tid >> 3,         cc0 = ((tid & 7) ^ (r0 & 7)) * 8;
    const int r1 = (256 + tid) >> 3, cc1 = ((tid & 7) ^ (r1 & 7)) * 8;

    for (int it = 0; it < 32; ++it) {
        const int kb = it * 64;
        __syncthreads();               // prior iter's sK/sVT reads done

        gload16(kbase + (kb + r0) * 64 + cc0, sK + (w * 64) * 8);        // K [key][d]
        gload16(kbase + (kb + r1) * 64 + cc1, sK + (256 + w * 64) * 8);
        gload16(vtbase + r0 * 2048 + kb + cc0, sVT + (w * 64) * 8);      // V^T [d][key]
        gload16(vtbase + r1 * 2048 + kb + cc1, sVT + (256 + w * 64) * 8);
        __syncthreads();               // staging resident

        // mask per key (key = kb + ktile*16 + q4*4 + r) — 4 aligned float4 loads
        float mkv[4][4];
#pragma unroll
        for (int ktile = 0; ktile < 4; ++ktile) {
            float4 m4 = *(const float4*)(mask + b * 2048 + kb + ktile * 16 + q4 * 4);
            mkv[ktile][0] = m4.x; mkv[ktile][1] = m4.y;
            mkv[ktile][2] = m4.z; mkv[ktile][3] = m4.w;
        }

        // --- S^T = K Q^T: D[key][qrow]; kf shared across rt
        f32x4 accST[4][2] = {};
#pragma unroll
        for (int kt = 0; kt < 2; ++kt) {
            bf16x8 kf[4];
#pragma unroll
            for (int ktile = 0; ktile < 4; ++ktile) {
                const int key = ktile * 16 + c15;
                const int cpos = (kt * 4 + q4) ^ (key & 7);
                kf[ktile] = *(const bf16x8*)(sK + key * 64 + cpos * 8);
            }
#pragma unroll
            for (int ktile = 0; ktile < 4; ++ktile)
#pragma unroll
                for (int rt = 0; rt < 2; ++rt)
                    accST[ktile][rt] = __builtin_amdgcn_mfma_f32_16x16x32_bf16(
                        kf[ktile], qf[rt][kt], accST[ktile][rt], 0, 0, 0);
        }

        // --- softmax in-register: p = exp(s/8 + mask); pack bf16 pairs per ktile
        u32 pu[4][2][2];
#pragma unroll
        for (int ktile = 0; ktile < 4; ++ktile)
#pragma unroll
            for (int rt = 0; rt < 2; ++rt) {
                u32 a[4];
#pragma unroll
                for (int r = 0; r < 4; ++r) {
                    const float p = __expf(fmaf(accST[ktile][rt][r], 0.125f, mkv[ktile][r]));
                    l_acc[rt] += p;
                    a[r] = __float_as_uint(p) + 0x8000u;   // bf16 bits in high half
                }
                pu[ktile][rt][0] = (a[0] >> 16) | (a[1] & 0xFFFF0000u);
                pu[ktile][rt][1] = (a[2] >> 16) | (a[3] & 0xFFFF0000u);
            }

        // --- PV with full K32, virtual key order k=(q4,j)->32g+16*(j>>2)+4*q4+(j&3)
#pragma unroll
        for (int g = 0; g < 2; ++g) {
            // A-frags: concatenation of ktile pair's packed registers (no LDS!)
            bf16x8 pA[2];
#pragma unroll
            for (int rt = 0; rt < 2; ++rt) {
                union { bf16x8 v; u32 u[4]; } t;
                t.u[0] = pu[2 * g][rt][0];
                t.u[1] = pu[2 * g][rt][1];
                t.u[2] = pu[2 * g + 1][rt][0];
                t.u[3] = pu[2 * g + 1][rt][1];
                pA[rt] = t.v;
            }
            // B-frags: V[key][d=nt*16+c15], keys 32g+4q4+{0..3} and 32g+16+4q4+{0..3}
            bf16x8 vB[4];
#pragma unroll
            for (int nt = 0; nt < 4; ++nt) {
                const int d = nt * 16 + c15;
                const int pc0 = (4 * g + (q4 >> 1)) ^ (d & 7);
                const int pc1 = (4 * g + 2 + (q4 >> 1)) ^ (d & 7);
                u32x2 v0 = *(const u32x2*)(sVT + d * 64 + pc0 * 8 + (q4 & 1) * 4);
                u32x2 v1 = *(const u32x2*)(sVT + d * 64 + pc1 * 8 + (q4 & 1) * 4);
                union { bf16x8 v; u32 u[4]; } t;
                t.u[0] = v0.x; t.u[1] = v0.y; t.u[2] = v1.x; t.u[3] = v1.y;
                vB[nt] = t.v;
            }
#pragma unroll
            for (int rt = 0; rt < 2; ++rt)
#pragma unroll
                for (int nt = 0; nt < 4; ++nt)
                    accO[rt][nt] = __builtin_amdgcn_mfma_f32_16x16x32_bf16(
                        pA[rt], vB[nt], accO[rt][nt], 0, 0, 0);
        }
    }

    // --- l reduction: across q4 groups -> total per qrow=c15
#pragma unroll
    for (int rt = 0; rt < 2; ++rt) {
        l_acc[rt] += __shfl_xor(l_acc[rt], 16);
        l_acc[rt] += __shfl_xor(l_acc[rt], 32);
    }

    // --- epilogue: accO C-layout row=q4*4+r=qrow, col=c15=d; l rebroadcast
    const int h = bh & 15;
#pragma unroll
    for (int rt = 0; rt < 2; ++rt) {
        float inv[4];
#pragma unroll
        for (int r = 0; r < 4; ++r)
            inv[r] = 1.0f / __shfl(l_acc[rt], q4 * 4 + r);
#pragma unroll
        for (int nt = 0; nt < 4; ++nt)
#pragma unroll
            for (int r = 0; r < 4; ++r) {
                const int qrow = qt * 128 + w * 32 + rt * 16 + q4 * 4 + r;
                const int d = nt * 16 + c15;
                out[(b * 2048 + qrow) * 1024 + h * 64 + d] = accO[rt][nt][r] * inv[r];
            }
    }
}

// ---------------------------------------------------------------------------
extern "C" void kernel_launch(void* const* d_in, const int* in_sizes, int n_in,
                              void* d_out, int out_size, void* d_ws, size_t ws_size,
                              hipStream_t stream)
{
    const float* hs   = (const float*)d_in[0];
    const float* mask = (const float*)d_in[1];
    const float* Wq   = (const float*)d_in[2];
    const float* bq   = (const float*)d_in[3];
    const float* Wk   = (const float*)d_in[4];
    const float* bk   = (const float*)d_in[5];
    const float* Wv   = (const float*)d_in[6];
    const float* bv   = (const float*)d_in[7];

    // workspace layout (u16 units)
    u16* ws   = (u16*)d_ws;
    u16* qw   = ws;                     // Q  [b,h,n,d] bf16
    u16* kw   = ws + 4194304;           // K  [b,h,n,d]
    u16* vtw  = ws + 8388608;           // V^T [b,h,d,n]
    u16* hsb  = ws + 12582912;          // hidden_states bf16 (cvt_all dst start)
    u16* wqb  = ws + 16777216;
    u16* wkb  = ws + 17825792;
    u16* wvb  = ws + 18874368;

    cvt_all<<<1024, 256, 0, stream>>>(hs, Wq, Wk, Wv, hsb);

    qkv_gemm<<<dim3(64, 24), 256, 0, stream>>>(hsb, wqb, wkb, wvb, bq, bk, bv, qw, kw, vtw);
    attn<<<dim3(16, 32), 256, 0, stream>>>(qw, kw, vtw, mask, (float*)d_out);
}